// Round 5
// baseline (368.664 us; speedup 1.0000x reference)
//
#include <hip/hip_runtime.h>
#include <math.h>
#include <cstdint>
#include <cstddef>

#define DI __device__ __forceinline__

typedef __bf16 bf16x8 __attribute__((ext_vector_type(8)));
typedef float f32x4 __attribute__((ext_vector_type(4)));

static constexpr int kB = 4, kS = 2048, kD = 1024;
static constexpr int kM = kB * kS;            // 8192 tokens
static constexpr float kScale = 0.03125f;     // 1/sqrt(1024)
static constexpr float kEps = 1e-5f;

DI unsigned short f2bf(float f) {
  unsigned u = __float_as_uint(f);
  u += 0x7FFFu + ((u >> 16) & 1u);   // round-to-nearest-even
  return (unsigned short)(u >> 16);
}
DI float bf2f(unsigned short h) {
  return __uint_as_float(((unsigned)h) << 16);
}

DI void gld_lds16(const void* g, void* l) {
  __builtin_amdgcn_global_load_lds(
      (__attribute__((address_space(1))) void*)(void*)g,
      (__attribute__((address_space(3))) void*)l, 16, 0, 0);
}

// ------- fused cast fp32 -> bf16 (x, Wq|Wk concat, Wv, W1, W2) -------
__global__ __launch_bounds__(256) void k_cast_all(
    const float* __restrict__ x, const float* __restrict__ Wq,
    const float* __restrict__ Wk, const float* __restrict__ Wv,
    const float* __restrict__ W1, const float* __restrict__ W2,
    unsigned short* __restrict__ xb, unsigned short* __restrict__ Wqkb,
    unsigned short* __restrict__ Wvb, unsigned short* __restrict__ W1b,
    unsigned short* __restrict__ W2b) {
  const int i = blockIdx.x * 256 + threadIdx.x;     // float4 index
  const int X4 = kM * kD / 4;                       // 2,097,152
  const int W4 = kD * kD / 4;                       // 262,144
  const float* src;
  unsigned short* dst;
  int j;
  if (i < X4) { src = x; dst = xb; j = i; }
  else if (i < X4 + W4)     { src = Wq; dst = Wqkb;          j = i - X4; }
  else if (i < X4 + 2 * W4) { src = Wk; dst = Wqkb + 4 * W4; j = i - X4 - W4; }
  else if (i < X4 + 3 * W4) { src = Wv; dst = Wvb;           j = i - X4 - 2 * W4; }
  else if (i < X4 + 4 * W4) { src = W1; dst = W1b;           j = i - X4 - 3 * W4; }
  else                      { src = W2; dst = W2b;           j = i - X4 - 4 * W4; }
  float4 v = ((const float4*)src)[j];
  ushort4 o;
  o.x = f2bf(v.x); o.y = f2bf(v.y); o.z = f2bf(v.z); o.w = f2bf(v.w);
  ((ushort4*)dst)[j] = o;
}

// ---------------- bf16 NT GEMM, 16x16x32 MFMA, XOR-swizzled LDS -------------
// (reverted to the round-3 core: 856 TF, 0 bank conflicts measured)
// C[M,N] = A[M,K] * B[N,K]^T (+bias, optional relu), batched via blockIdx.z.
// CAUSAL: 0 none; 1 lower-triangle compact grid (blockIdx.x = tri index);
//         2 clamp K-loop at bm+128, longest-first y order.
// LDS tile [row][kchunk]: chunk kc of row r stored at slot kc ^ (r&7); the
// fragment ds_read_b128 then spreads 8 accesses/bank (minimum). Staging keeps
// dst = wave-uniform base + lane*16 (global_load_lds constraint); the GLOBAL
// chunk each lane fetches is XOR-permuted within its 128B segment.
template <int OUT_BF16, int RELU, int CAUSAL>
__global__ __launch_bounds__(256, 2) void k_gemm_nt(
    const unsigned short* __restrict__ A, const unsigned short* __restrict__ B,
    void* __restrict__ Cv, const float* __restrict__ bias,
    int M, int N, int K, int lda, int ldb, int ldc,
    long sA, long sB, long sC) {
  int bm, bn;
  if (CAUSAL == 1) {
    const int t = blockIdx.x;
    int r = (int)floorf((sqrtf(8.f * (float)t + 1.f) - 1.f) * 0.5f);
    while ((r + 1) * (r + 2) / 2 <= t) ++r;
    while (r * (r + 1) / 2 > t) --r;
    bm = r * 128;
    bn = (t - r * (r + 1) / 2) * 128;
  } else if (CAUSAL == 2) {
    bm = (gridDim.y - 1 - blockIdx.y) * 128;   // longest K-loop first
    bn = blockIdx.x * 128;
  } else {
    bm = blockIdx.y * 128;
    bn = blockIdx.x * 128;
  }
  A += (long)blockIdx.z * sA;
  B += (long)blockIdx.z * sB;
  const int Keff = (CAUSAL == 2) ? ((K < bm + 128) ? K : bm + 128) : K;

  const int tid = threadIdx.x;
  const int lane = tid & 63;
  const int wm = ((tid >> 6) >> 1) * 64;   // wave row offset in tile
  const int wn = ((tid >> 6) & 1) * 64;    // wave col offset in tile

  __shared__ __align__(16) unsigned short Asm[128 * 64];
  __shared__ __align__(16) unsigned short Bsm[128 * 64];

  f32x4 acc[4][4];
#pragma unroll
  for (int i = 0; i < 4; ++i)
#pragma unroll
    for (int j = 0; j < 4; ++j) acc[i][j] = (f32x4){0.f, 0.f, 0.f, 0.f};

  const int r_row = tid >> 3;                              // 0..31
  const int dst_k = (tid & 7) * 8;                         // LDS slot (linear)
  const int src_k = ((tid & 7) ^ ((tid >> 3) & 7)) * 8;    // swizzled global chunk
  const int fm = lane & 15;
  const int fq = lane >> 4;                                // quad 0..3

  for (int k0 = 0; k0 < Keff; k0 += 64) {
#pragma unroll
    for (int i = 0; i < 4; ++i) {
      const int row = i * 32 + r_row;
      gld_lds16(A + (long)(bm + row) * lda + (k0 + src_k), Asm + row * 64 + dst_k);
      gld_lds16(B + (long)(bn + row) * ldb + (k0 + src_k), Bsm + row * 64 + dst_k);
    }
    __syncthreads();
#pragma unroll
    for (int kk = 0; kk < 2; ++kk) {
      bf16x8 af[4], bfr[4];
#pragma unroll
      for (int i = 0; i < 4; ++i) {
        const int pa = ((kk * 4 + fq) ^ (fm & 7)) * 8;
        af[i]  = *(const bf16x8*)(Asm + (wm + i * 16 + fm) * 64 + pa);
        bfr[i] = *(const bf16x8*)(Bsm + (wn + i * 16 + fm) * 64 + pa);
      }
#pragma unroll
      for (int i = 0; i < 4; ++i)
#pragma unroll
        for (int j = 0; j < 4; ++j)
          acc[i][j] = __builtin_amdgcn_mfma_f32_16x16x32_bf16(af[i], bfr[j], acc[i][j], 0, 0, 0);
    }
    __syncthreads();
  }

  const long cb = (long)blockIdx.z * sC;
#pragma unroll
  for (int i = 0; i < 4; ++i) {
#pragma unroll
    for (int j = 0; j < 4; ++j) {
      const int col = bn + wn + j * 16 + fm;       // C/D: col = lane&15
      const float bv = bias ? bias[col] : 0.f;
#pragma unroll
      for (int r = 0; r < 4; ++r) {
        const int row = bm + wm + i * 16 + fq * 4 + r;  // row = quad*4 + reg
        float v = acc[i][j][r] + bv;
        if (RELU) v = fmaxf(v, 0.f);
        if (OUT_BF16)
          ((unsigned short*)Cv)[cb + (long)row * ldc + col] = f2bf(v);
        else
          ((float*)Cv)[cb + (long)row * ldc + col] = v;
      }
    }
  }
}

// ---------------- wave reductions ----------------
DI float wsum(float v) {
  v += __shfl_xor(v, 32, 64);
  v += __shfl_xor(v, 16, 64);
  v += __shfl_xor(v, 8, 64);
  v += __shfl_xor(v, 4, 64);
  v += __shfl_xor(v, 2, 64);
  v += __shfl_xor(v, 1, 64);
  return v;
}
DI float wmax(float v) {
  v = fmaxf(v, __shfl_xor(v, 32, 64));
  v = fmaxf(v, __shfl_xor(v, 16, 64));
  v = fmaxf(v, __shfl_xor(v, 8, 64));
  v = fmaxf(v, __shfl_xor(v, 4, 64));
  v = fmaxf(v, __shfl_xor(v, 2, 64));
  v = fmaxf(v, __shfl_xor(v, 1, 64));
  return v;
}

// ---------------- causal softmax: scores bf16 -> P bf16 ----------------
__global__ __launch_bounds__(256) void k_softmax_causal(
    const unsigned short* __restrict__ S, unsigned short* __restrict__ P) {
  const int row = blockIdx.x;           // 0..8191 flat (b*2048+q)
  const int q = row & (kS - 1);
  const int lim = (q & ~127) + 128;     // attn GEMM reads only k < lim
  const unsigned short* Srow = S + (long)row * kS;
  unsigned short* Prow = P + (long)row * kS;
  const int tid = threadIdx.x;
  __shared__ float red[4];

  float v[8];
  float mx = -INFINITY;
#pragma unroll
  for (int i = 0; i < 8; ++i) {
    const int k = tid + i * 256;
    float xv = -INFINITY;
    if (k <= q) xv = bf2f(Srow[k]) * kScale;
    v[i] = xv;
    mx = fmaxf(mx, xv);
  }
  mx = wmax(mx);
  if ((tid & 63) == 0) red[tid >> 6] = mx;
  __syncthreads();
  mx = fmaxf(fmaxf(red[0], red[1]), fmaxf(red[2], red[3]));
  __syncthreads();  // red reused below

  float sum = 0.f;
#pragma unroll
  for (int i = 0; i < 8; ++i) {
    const float e = (v[i] > -INFINITY) ? __expf(v[i] - mx) : 0.f;
    v[i] = e;
    sum += e;
  }
  sum = wsum(sum);
  if ((tid & 63) == 0) red[tid >> 6] = sum;
  __syncthreads();
  sum = red[0] + red[1] + red[2] + red[3];
  const float inv = 1.f / sum;
#pragma unroll
  for (int i = 0; i < 8; ++i) {
    const int k = tid + i * 256;
    if (k < lim) Prow[k] = f2bf(v[i] * inv);
  }
}

// ---------------- fused residual + layernorm ----------------
template <int WRITE_BF16>
__global__ __launch_bounds__(256) void k_residual_ln(
    const float* __restrict__ X, const float* __restrict__ Y,
    const float* __restrict__ gamma, const float* __restrict__ beta,
    float* __restrict__ Out, unsigned short* __restrict__ OutB) {
  const long base = (long)blockIdx.x * kD;
  const int tid = threadIdx.x;
  __shared__ float reds[4], redss[4];
  float v[4];
  float s = 0.f, ss2 = 0.f;
#pragma unroll
  for (int i = 0; i < 4; ++i) {
    const int k = tid + i * 256;
    const float xv = X[base + k] + Y[base + k];
    v[i] = xv;
    s += xv;
    ss2 += xv * xv;
  }
  s = wsum(s);
  ss2 = wsum(ss2);
  if ((tid & 63) == 0) { reds[tid >> 6] = s; redss[tid >> 6] = ss2; }
  __syncthreads();
  s = reds[0] + reds[1] + reds[2] + reds[3];
  ss2 = redss[0] + redss[1] + redss[2] + redss[3];
  const float mu = s * (1.f / kD);
  float var = ss2 * (1.f / kD) - mu * mu;
  var = fmaxf(var, 0.f);
  const float rstd = rsqrtf(var + kEps);
#pragma unroll
  for (int i = 0; i < 4; ++i) {
    const int k = tid + i * 256;
    const float y = (v[i] - mu) * rstd * gamma[k] + beta[k];
    Out[base + k] = y;
    if (WRITE_BF16) OutB[base + k] = f2bf(y);
  }
}

extern "C" void kernel_launch(void* const* d_in, const int* in_sizes, int n_in,
                              void* d_out, int out_size, void* d_ws, size_t ws_size,
                              hipStream_t stream) {
  (void)in_sizes; (void)n_in; (void)out_size; (void)ws_size;
  const float* x     = (const float*)d_in[0];
  const float* Wq    = (const float*)d_in[1];
  const float* Wk    = (const float*)d_in[2];
  const float* Wv    = (const float*)d_in[3];
  const float* W1    = (const float*)d_in[4];
  const float* b1    = (const float*)d_in[5];
  const float* W2    = (const float*)d_in[6];
  const float* b2    = (const float*)d_in[7];
  const float* gamma = (const float*)d_in[8];
  const float* beta  = (const float*)d_in[9];
  float* out = (float*)d_out;

  char* base = (char*)d_ws;
  size_t off = 0;
  auto alloc = [&](size_t bytes) -> void* {
    void* p = base + off;
    off = (off + bytes + 255) & ~(size_t)255;
    return p;
  };

  unsigned short* xb   = (unsigned short*)alloc((size_t)kM * kD * 2);        // 16 MB
  unsigned short* Wqkb = (unsigned short*)alloc((size_t)2 * kD * kD * 2);    // 4 MB
  unsigned short* Wvb  = (unsigned short*)alloc((size_t)kD * kD * 2);        // 2 MB
  unsigned short* W1b  = (unsigned short*)alloc((size_t)kD * kD * 2);        // 2 MB
  unsigned short* W2b  = (unsigned short*)alloc((size_t)kD * kD * 2);        // 2 MB
  unsigned short* QKb  = (unsigned short*)alloc((size_t)kM * 2 * kD * 2);    // 32 MB
  unsigned short* Vt   = (unsigned short*)alloc((size_t)kM * kD * 2);        // 16 MB
  unsigned short* Sb   = (unsigned short*)alloc((size_t)kB * kS * kS * 2);   // 32 MB
  unsigned short* Pb   = (unsigned short*)alloc((size_t)kB * kS * kS * 2);   // 32 MB
  float*          attn = (float*)alloc((size_t)kM * kD * 4);                 // 32 MB
  float*          h    = (float*)alloc((size_t)kM * kD * 4);                 // 32 MB
  float*          ff   = attn;               // attn dead after LN1
  unsigned short* hb   = Sb;                 // scores dead after softmax
  unsigned short* mid  = Pb;                 // P dead after attn GEMM

  dim3 blk(256);

  // fused casts
  {
    const int n4 = (kM * kD + 5 * kD * kD) / 4;
    k_cast_all<<<n4 / 256, blk, 0, stream>>>(x, Wq, Wk, Wv, W1, W2,
                                             xb, Wqkb, Wvb, W1b, W2b);
  }

  // QK projection: [8192x1024] x [2048x1024]^T -> QK [8192x2048]
  k_gemm_nt<1, 0, 0><<<dim3(2 * kD / 128, kM / 128, 1), blk, 0, stream>>>(
      xb, Wqkb, QKb, nullptr, kM, 2 * kD, kD, kD, kD, 2 * kD, 0, 0, 0);

  // Vt[b] = Wv x_b^T : [1024x1024] x [2048x1024]^T -> [1024x2048] per batch
  k_gemm_nt<1, 0, 0><<<dim3(kS / 128, kD / 128, kB), blk, 0, stream>>>(
      Wvb, xb, Vt, nullptr, kD, kS, kD, kD, kD, kS,
      0, (long)kS * kD, (long)kD * kS);

  // scores = Q K^T (bf16 out), lower-triangle compact grid
  k_gemm_nt<1, 0, 1><<<dim3(136, 1, kB), blk, 0, stream>>>(
      QKb, QKb + kD, Sb, nullptr, kS, kS, kD, 2 * kD, 2 * kD, kS,
      (long)kS * 2 * kD, (long)kS * 2 * kD, (long)kS * kS);

  // causal softmax -> P bf16 (writes only k < diagonal tile edge)
  k_softmax_causal<<<kM, blk, 0, stream>>>(Sb, Pb);

  // attn = P Vt^T (K-loop clamped at diagonal, longest-first)
  k_gemm_nt<0, 0, 2><<<dim3(kD / 128, kS / 128, kB), blk, 0, stream>>>(
      Pb, Vt, attn, nullptr, kS, kD, kS, kS, kS, kD,
      (long)kS * kS, (long)kD * kS, (long)kS * kD);

  // h = LN(x + attn), also bf16 copy
  k_residual_ln<1><<<kM, blk, 0, stream>>>(x, attn, gamma, beta, h, hb);

  // FFN
  k_gemm_nt<1, 1, 0><<<dim3(kD / 128, kM / 128, 1), blk, 0, stream>>>(
      hb, W1b, mid, b1, kM, kD, kD, kD, kD, kD, 0, 0, 0);
  k_gemm_nt<0, 0, 0><<<dim3(kD / 128, kM / 128, 1), blk, 0, stream>>>(
      mid, W2b, ff, b2, kM, kD, kD, kD, kD, kD, 0, 0, 0);

  // out = LN(h + ff)
  k_residual_ln<0><<<kM, blk, 0, stream>>>(h, ff, gamma, beta, out, nullptr);
}

// Round 6
// 347.630 us; speedup vs baseline: 1.0605x; 1.0605x over previous
//
#include <hip/hip_runtime.h>
#include <math.h>
#include <cstdint>
#include <cstddef>

#define DI __device__ __forceinline__

typedef __bf16 bf16x8 __attribute__((ext_vector_type(8)));
typedef float f32x4 __attribute__((ext_vector_type(4)));

static constexpr int kB = 4, kS = 2048, kD = 1024;
static constexpr int kM = kB * kS;            // 8192 tokens
static constexpr float kScale = 0.03125f;     // 1/sqrt(1024)
static constexpr float kEps = 1e-5f;

DI unsigned short f2bf(float f) {
  unsigned u = __float_as_uint(f);
  u += 0x7FFFu + ((u >> 16) & 1u);   // round-to-nearest-even
  return (unsigned short)(u >> 16);
}
DI float bf2f(unsigned short h) {
  return __uint_as_float(((unsigned)h) << 16);
}

DI void gld_lds16(const void* g, void* l) {
  __builtin_amdgcn_global_load_lds(
      (__attribute__((address_space(1))) void*)(void*)g,
      (__attribute__((address_space(3))) void*)l, 16, 0, 0);
}

// ------- fused cast fp32 -> bf16 (x, Wq|Wk concat, Wv, W1, W2) -------
__global__ __launch_bounds__(256) void k_cast_all(
    const float* __restrict__ x, const float* __restrict__ Wq,
    const float* __restrict__ Wk, const float* __restrict__ Wv,
    const float* __restrict__ W1, const float* __restrict__ W2,
    unsigned short* __restrict__ xb, unsigned short* __restrict__ Wqkb,
    unsigned short* __restrict__ Wvb, unsigned short* __restrict__ W1b,
    unsigned short* __restrict__ W2b) {
  const int i = blockIdx.x * 256 + threadIdx.x;     // float4 index
  const int X4 = kM * kD / 4;                       // 2,097,152
  const int W4 = kD * kD / 4;                       // 262,144
  const float* src;
  unsigned short* dst;
  int j;
  if (i < X4) { src = x; dst = xb; j = i; }
  else if (i < X4 + W4)     { src = Wq; dst = Wqkb;          j = i - X4; }
  else if (i < X4 + 2 * W4) { src = Wk; dst = Wqkb + 4 * W4; j = i - X4 - W4; }
  else if (i < X4 + 3 * W4) { src = Wv; dst = Wvb;           j = i - X4 - 2 * W4; }
  else if (i < X4 + 4 * W4) { src = W1; dst = W1b;           j = i - X4 - 3 * W4; }
  else                      { src = W2; dst = W2b;           j = i - X4 - 4 * W4; }
  float4 v = ((const float4*)src)[j];
  ushort4 o;
  o.x = f2bf(v.x); o.y = f2bf(v.y); o.z = f2bf(v.z); o.w = f2bf(v.w);
  ((ushort4*)dst)[j] = o;
}

// ---------------- bf16 NT GEMM, 16x16x32 MFMA, XOR-swizzled LDS -------------
// C[M,N] = A[M,K] * B[N,K]^T (+bias, optional relu), batched via blockIdx.z.
// CAUSAL: 0 none; 1 lower-triangle compact grid (blockIdx.x = tri index);
//         2 clamp K-loop at bm+128, longest-first y order (no XCD remap:
//         gridDim.x=8 already pins B-column tiles to XCDs round-robin).
// XCD remap (CAUSAL 0/1): HW dispatches consecutive linear block ids round-
// robin over 8 XCDs; lin=(lin&7)*(nblk/8)+(lin>>3) gives each XCD a contiguous
// work span so A-row-tiles are fetched into exactly one XCD L2 and the B panel
// stays L2-resident (FFN: 2MB A-span + 2MB B = exact 4MB fit).
// LDS tile [row][kchunk]: chunk kc of row r stored at slot kc ^ (r&7); the
// fragment ds_read_b128 then spreads 8 accesses/bank (minimum, 0 conflicts
// measured). Staging keeps dst = wave-uniform base + lane*16.
template <int OUT_BF16, int RELU, int CAUSAL>
__global__ __launch_bounds__(256, 2) void k_gemm_nt(
    const unsigned short* __restrict__ A, const unsigned short* __restrict__ B,
    void* __restrict__ Cv, const float* __restrict__ bias,
    int M, int N, int K, int lda, int ldb, int ldc,
    long sA, long sB, long sC) {
  int bm, bn;
  {
    int lin = blockIdx.x + gridDim.x * blockIdx.y;
    const int nblk = gridDim.x * gridDim.y;
    if (CAUSAL != 2 && (nblk & 7) == 0)
      lin = (lin & 7) * (nblk >> 3) + (lin >> 3);
    if (CAUSAL == 1) {
      const int t = lin;
      int r = (int)floorf((sqrtf(8.f * (float)t + 1.f) - 1.f) * 0.5f);
      while ((r + 1) * (r + 2) / 2 <= t) ++r;
      while (r * (r + 1) / 2 > t) --r;
      bm = r * 128;
      bn = (t - r * (r + 1) / 2) * 128;
    } else if (CAUSAL == 2) {
      bm = (gridDim.y - 1 - blockIdx.y) * 128;   // longest K-loop first
      bn = blockIdx.x * 128;
    } else {
      bm = (lin / gridDim.x) * 128;
      bn = (lin % gridDim.x) * 128;
    }
  }
  A += (long)blockIdx.z * sA;
  B += (long)blockIdx.z * sB;
  const int Keff = (CAUSAL == 2) ? ((K < bm + 128) ? K : bm + 128) : K;

  const int tid = threadIdx.x;
  const int lane = tid & 63;
  const int wm = ((tid >> 6) >> 1) * 64;   // wave row offset in tile
  const int wn = ((tid >> 6) & 1) * 64;    // wave col offset in tile

  __shared__ __align__(16) unsigned short Asm[128 * 64];
  __shared__ __align__(16) unsigned short Bsm[128 * 64];

  f32x4 acc[4][4];
#pragma unroll
  for (int i = 0; i < 4; ++i)
#pragma unroll
    for (int j = 0; j < 4; ++j) acc[i][j] = (f32x4){0.f, 0.f, 0.f, 0.f};

  const int r_row = tid >> 3;                              // 0..31
  const int dst_k = (tid & 7) * 8;                         // LDS slot (linear)
  const int src_k = ((tid & 7) ^ ((tid >> 3) & 7)) * 8;    // swizzled global chunk
  const int fm = lane & 15;
  const int fq = lane >> 4;                                // quad 0..3

  for (int k0 = 0; k0 < Keff; k0 += 64) {
#pragma unroll
    for (int i = 0; i < 4; ++i) {
      const int row = i * 32 + r_row;
      gld_lds16(A + (long)(bm + row) * lda + (k0 + src_k), Asm + row * 64 + dst_k);
      gld_lds16(B + (long)(bn + row) * ldb + (k0 + src_k), Bsm + row * 64 + dst_k);
    }
    __syncthreads();
#pragma unroll
    for (int kk = 0; kk < 2; ++kk) {
      bf16x8 af[4], bfr[4];
#pragma unroll
      for (int i = 0; i < 4; ++i) {
        const int pa = ((kk * 4 + fq) ^ (fm & 7)) * 8;
        af[i]  = *(const bf16x8*)(Asm + (wm + i * 16 + fm) * 64 + pa);
        bfr[i] = *(const bf16x8*)(Bsm + (wn + i * 16 + fm) * 64 + pa);
      }
#pragma unroll
      for (int i = 0; i < 4; ++i)
#pragma unroll
        for (int j = 0; j < 4; ++j)
          acc[i][j] = __builtin_amdgcn_mfma_f32_16x16x32_bf16(af[i], bfr[j], acc[i][j], 0, 0, 0);
    }
    __syncthreads();
  }

  const long cb = (long)blockIdx.z * sC;
#pragma unroll
  for (int i = 0; i < 4; ++i) {
#pragma unroll
    for (int j = 0; j < 4; ++j) {
      const int col = bn + wn + j * 16 + fm;       // C/D: col = lane&15
      const float bv = bias ? bias[col] : 0.f;
#pragma unroll
      for (int r = 0; r < 4; ++r) {
        const int row = bm + wm + i * 16 + fq * 4 + r;  // row = quad*4 + reg
        float v = acc[i][j][r] + bv;
        if (RELU) v = fmaxf(v, 0.f);
        if (OUT_BF16)
          ((unsigned short*)Cv)[cb + (long)row * ldc + col] = f2bf(v);
        else
          ((float*)Cv)[cb + (long)row * ldc + col] = v;
      }
    }
  }
}

// ---------------- wave reductions ----------------
DI float wsum(float v) {
  v += __shfl_xor(v, 32, 64);
  v += __shfl_xor(v, 16, 64);
  v += __shfl_xor(v, 8, 64);
  v += __shfl_xor(v, 4, 64);
  v += __shfl_xor(v, 2, 64);
  v += __shfl_xor(v, 1, 64);
  return v;
}
DI float wmax(float v) {
  v = fmaxf(v, __shfl_xor(v, 32, 64));
  v = fmaxf(v, __shfl_xor(v, 16, 64));
  v = fmaxf(v, __shfl_xor(v, 8, 64));
  v = fmaxf(v, __shfl_xor(v, 4, 64));
  v = fmaxf(v, __shfl_xor(v, 2, 64));
  v = fmaxf(v, __shfl_xor(v, 1, 64));
  return v;
}

// ---------------- causal softmax: scores bf16 -> P bf16 ----------------
__global__ __launch_bounds__(256) void k_softmax_causal(
    const unsigned short* __restrict__ S, unsigned short* __restrict__ P) {
  const int row = blockIdx.x;           // 0..8191 flat (b*2048+q)
  const int q = row & (kS - 1);
  const int lim = (q & ~127) + 128;     // attn GEMM reads only k < lim
  const unsigned short* Srow = S + (long)row * kS;
  unsigned short* Prow = P + (long)row * kS;
  const int tid = threadIdx.x;
  __shared__ float red[4];

  float v[8];
  float mx = -INFINITY;
#pragma unroll
  for (int i = 0; i < 8; ++i) {
    const int k = tid + i * 256;
    float xv = -INFINITY;
    if (k <= q) xv = bf2f(Srow[k]) * kScale;
    v[i] = xv;
    mx = fmaxf(mx, xv);
  }
  mx = wmax(mx);
  if ((tid & 63) == 0) red[tid >> 6] = mx;
  __syncthreads();
  mx = fmaxf(fmaxf(red[0], red[1]), fmaxf(red[2], red[3]));
  __syncthreads();  // red reused below

  float sum = 0.f;
#pragma unroll
  for (int i = 0; i < 8; ++i) {
    const float e = (v[i] > -INFINITY) ? __expf(v[i] - mx) : 0.f;
    v[i] = e;
    sum += e;
  }
  sum = wsum(sum);
  if ((tid & 63) == 0) red[tid >> 6] = sum;
  __syncthreads();
  sum = red[0] + red[1] + red[2] + red[3];
  const float inv = 1.f / sum;
#pragma unroll
  for (int i = 0; i < 8; ++i) {
    const int k = tid + i * 256;
    if (k < lim) Prow[k] = f2bf(v[i] * inv);
  }
}

// ---------------- fused residual + layernorm (Y branch in bf16) -------------
template <int WRITE_BF16>
__global__ __launch_bounds__(256) void k_residual_ln(
    const float* __restrict__ X, const unsigned short* __restrict__ Yb,
    const float* __restrict__ gamma, const float* __restrict__ beta,
    float* __restrict__ Out, unsigned short* __restrict__ OutB) {
  const long base = (long)blockIdx.x * kD;
  const int tid = threadIdx.x;
  __shared__ float reds[4], redss[4];
  float v[4];
  float s = 0.f, ss2 = 0.f;
#pragma unroll
  for (int i = 0; i < 4; ++i) {
    const int k = tid + i * 256;
    const float xv = X[base + k] + bf2f(Yb[base + k]);
    v[i] = xv;
    s += xv;
    ss2 += xv * xv;
  }
  s = wsum(s);
  ss2 = wsum(ss2);
  if ((tid & 63) == 0) { reds[tid >> 6] = s; redss[tid >> 6] = ss2; }
  __syncthreads();
  s = reds[0] + reds[1] + reds[2] + reds[3];
  ss2 = redss[0] + redss[1] + redss[2] + redss[3];
  const float mu = s * (1.f / kD);
  float var = ss2 * (1.f / kD) - mu * mu;
  var = fmaxf(var, 0.f);
  const float rstd = rsqrtf(var + kEps);
#pragma unroll
  for (int i = 0; i < 4; ++i) {
    const int k = tid + i * 256;
    const float y = (v[i] - mu) * rstd * gamma[k] + beta[k];
    Out[base + k] = y;
    if (WRITE_BF16) OutB[base + k] = f2bf(y);
  }
}

extern "C" void kernel_launch(void* const* d_in, const int* in_sizes, int n_in,
                              void* d_out, int out_size, void* d_ws, size_t ws_size,
                              hipStream_t stream) {
  (void)in_sizes; (void)n_in; (void)out_size; (void)ws_size;
  const float* x     = (const float*)d_in[0];
  const float* Wq    = (const float*)d_in[1];
  const float* Wk    = (const float*)d_in[2];
  const float* Wv    = (const float*)d_in[3];
  const float* W1    = (const float*)d_in[4];
  const float* b1    = (const float*)d_in[5];
  const float* W2    = (const float*)d_in[6];
  const float* b2    = (const float*)d_in[7];
  const float* gamma = (const float*)d_in[8];
  const float* beta  = (const float*)d_in[9];
  float* out = (float*)d_out;

  char* base = (char*)d_ws;
  size_t off = 0;
  auto alloc = [&](size_t bytes) -> void* {
    void* p = base + off;
    off = (off + bytes + 255) & ~(size_t)255;
    return p;
  };

  unsigned short* xb     = (unsigned short*)alloc((size_t)kM * kD * 2);       // 16 MB
  unsigned short* Wqkb   = (unsigned short*)alloc((size_t)2 * kD * kD * 2);   // 4 MB
  unsigned short* Wvb    = (unsigned short*)alloc((size_t)kD * kD * 2);       // 2 MB
  unsigned short* W1b    = (unsigned short*)alloc((size_t)kD * kD * 2);       // 2 MB
  unsigned short* W2b    = (unsigned short*)alloc((size_t)kD * kD * 2);       // 2 MB
  unsigned short* QKb    = (unsigned short*)alloc((size_t)kM * 2 * kD * 2);   // 32 MB
  unsigned short* Vt     = (unsigned short*)alloc((size_t)kM * kD * 2);       // 16 MB
  unsigned short* Sb     = (unsigned short*)alloc((size_t)kB * kS * kS * 2);  // 32 MB
  unsigned short* Pb     = (unsigned short*)alloc((size_t)kB * kS * kS * 2);  // 32 MB
  unsigned short* attn_b = (unsigned short*)alloc((size_t)kM * kD * 2);       // 16 MB
  float*          h      = (float*)alloc((size_t)kM * kD * 4);                // 32 MB
  unsigned short* ff_b = attn_b;             // attn dead after LN1
  unsigned short* hb   = Sb;                 // scores dead after softmax
  unsigned short* mid  = Pb;                 // P dead after attn GEMM

  dim3 blk(256);

  // fused casts
  {
    const int n4 = (kM * kD + 5 * kD * kD) / 4;
    k_cast_all<<<n4 / 256, blk, 0, stream>>>(x, Wq, Wk, Wv, W1, W2,
                                             xb, Wqkb, Wvb, W1b, W2b);
  }

  // QK projection: [8192x1024] x [2048x1024]^T -> QK [8192x2048]
  k_gemm_nt<1, 0, 0><<<dim3(2 * kD / 128, kM / 128, 1), blk, 0, stream>>>(
      xb, Wqkb, QKb, nullptr, kM, 2 * kD, kD, kD, kD, 2 * kD, 0, 0, 0);

  // Vt[b] = Wv x_b^T : [1024x1024] x [2048x1024]^T -> [1024x2048] per batch
  k_gemm_nt<1, 0, 0><<<dim3(kS / 128, kD / 128, kB), blk, 0, stream>>>(
      Wvb, xb, Vt, nullptr, kD, kS, kD, kD, kD, kS,
      0, (long)kS * kD, (long)kD * kS);

  // scores = Q K^T (bf16 out), lower-triangle compact grid
  k_gemm_nt<1, 0, 1><<<dim3(136, 1, kB), blk, 0, stream>>>(
      QKb, QKb + kD, Sb, nullptr, kS, kS, kD, 2 * kD, 2 * kD, kS,
      (long)kS * 2 * kD, (long)kS * 2 * kD, (long)kS * kS);

  // causal softmax -> P bf16 (writes only k < diagonal tile edge)
  k_softmax_causal<<<kM, blk, 0, stream>>>(Sb, Pb);

  // attn = P Vt^T (K-loop clamped at diagonal, longest-first), bf16 out
  k_gemm_nt<1, 0, 2><<<dim3(kD / 128, kS / 128, kB), blk, 0, stream>>>(
      Pb, Vt, attn_b, nullptr, kS, kD, kS, kS, kS, kD,
      (long)kS * kS, (long)kD * kS, (long)kS * kD);

  // h = LN(x + attn), also bf16 copy
  k_residual_ln<1><<<kM, blk, 0, stream>>>(x, attn_b, gamma, beta, h, hb);

  // FFN
  k_gemm_nt<1, 1, 0><<<dim3(kD / 128, kM / 128, 1), blk, 0, stream>>>(
      hb, W1b, mid, b1, kM, kD, kD, kD, kD, kD, 0, 0, 0);
  k_gemm_nt<1, 0, 0><<<dim3(kD / 128, kM / 128, 1), blk, 0, stream>>>(
      mid, W2b, ff_b, b2, kM, kD, kD, kD, kD, kD, 0, 0, 0);

  // out = LN(h + ff)
  k_residual_ln<0><<<kM, blk, 0, stream>>>(h, ff_b, gamma, beta, out, nullptr);
}

// Round 7
// 342.166 us; speedup vs baseline: 1.0774x; 1.0160x over previous
//
#include <hip/hip_runtime.h>
#include <math.h>
#include <cstdint>
#include <cstddef>

#define DI __device__ __forceinline__

typedef __bf16 bf16x8 __attribute__((ext_vector_type(8)));
typedef float f32x4 __attribute__((ext_vector_type(4)));

static constexpr int kB = 4, kS = 2048, kD = 1024;
static constexpr int kM = kB * kS;            // 8192 tokens
static constexpr float kScale = 0.03125f;     // 1/sqrt(1024)
static constexpr float kEps = 1e-5f;

DI unsigned short f2bf(float f) {
  unsigned u = __float_as_uint(f);
  u += 0x7FFFu + ((u >> 16) & 1u);   // round-to-nearest-even
  return (unsigned short)(u >> 16);
}
DI float bf2f(unsigned short h) {
  return __uint_as_float(((unsigned)h) << 16);
}

DI void gld_lds16(const void* g, void* l) {
  __builtin_amdgcn_global_load_lds(
      (__attribute__((address_space(1))) void*)(void*)g,
      (__attribute__((address_space(3))) void*)l, 16, 0, 0);
}

// ------- fused cast fp32 -> bf16 (x, Wq|Wk concat, Wv, W1, W2) -------
__global__ __launch_bounds__(256) void k_cast_all(
    const float* __restrict__ x, const float* __restrict__ Wq,
    const float* __restrict__ Wk, const float* __restrict__ Wv,
    const float* __restrict__ W1, const float* __restrict__ W2,
    unsigned short* __restrict__ xb, unsigned short* __restrict__ Wqkb,
    unsigned short* __restrict__ Wvb, unsigned short* __restrict__ W1b,
    unsigned short* __restrict__ W2b) {
  const int i = blockIdx.x * 256 + threadIdx.x;     // float4 index
  const int X4 = kM * kD / 4;                       // 2,097,152
  const int W4 = kD * kD / 4;                       // 262,144
  const float* src;
  unsigned short* dst;
  int j;
  if (i < X4) { src = x; dst = xb; j = i; }
  else if (i < X4 + W4)     { src = Wq; dst = Wqkb;          j = i - X4; }
  else if (i < X4 + 2 * W4) { src = Wk; dst = Wqkb + 4 * W4; j = i - X4 - W4; }
  else if (i < X4 + 3 * W4) { src = Wv; dst = Wvb;           j = i - X4 - 2 * W4; }
  else if (i < X4 + 4 * W4) { src = W1; dst = W1b;           j = i - X4 - 3 * W4; }
  else                      { src = W2; dst = W2b;           j = i - X4 - 4 * W4; }
  float4 v = ((const float4*)src)[j];
  ushort4 o;
  o.x = f2bf(v.x); o.y = f2bf(v.y); o.z = f2bf(v.z); o.w = f2bf(v.w);
  ((ushort4*)dst)[j] = o;
}

// ---------------- bf16 NT GEMM, 16x16x32 MFMA, XOR-swizzled LDS -------------
// C[M,N] = A[M,K] * B[N,K]^T (+bias, optional relu), batched via blockIdx.z.
// CAUSAL: 0 none; 1 lower-triangle compact grid (blockIdx.x = tri index).
// XCD remap: lin=(lin&7)*(nblk/8)+(lin>>3) gives each XCD a contiguous span.
// LDS tile [row][kchunk]: chunk kc of row r stored at slot kc ^ (r&7);
// fragment ds_read_b128 spreads 8 accesses/bank (0 conflicts measured).
template <int OUT_BF16, int RELU, int CAUSAL>
__global__ __launch_bounds__(256, 2) void k_gemm_nt(
    const unsigned short* __restrict__ A, const unsigned short* __restrict__ B,
    void* __restrict__ Cv, const float* __restrict__ bias,
    int M, int N, int K, int lda, int ldb, int ldc,
    long sA, long sB, long sC) {
  int bm, bn;
  {
    int lin = blockIdx.x + gridDim.x * blockIdx.y;
    const int nblk = gridDim.x * gridDim.y;
    if ((nblk & 7) == 0)
      lin = (lin & 7) * (nblk >> 3) + (lin >> 3);
    if (CAUSAL == 1) {
      const int t = lin;
      int r = (int)floorf((sqrtf(8.f * (float)t + 1.f) - 1.f) * 0.5f);
      while ((r + 1) * (r + 2) / 2 <= t) ++r;
      while (r * (r + 1) / 2 > t) --r;
      bm = r * 128;
      bn = (t - r * (r + 1) / 2) * 128;
    } else {
      bm = (lin / gridDim.x) * 128;
      bn = (lin % gridDim.x) * 128;
    }
  }
  A += (long)blockIdx.z * sA;
  B += (long)blockIdx.z * sB;

  const int tid = threadIdx.x;
  const int lane = tid & 63;
  const int wm = ((tid >> 6) >> 1) * 64;   // wave row offset in tile
  const int wn = ((tid >> 6) & 1) * 64;    // wave col offset in tile

  __shared__ __align__(16) unsigned short Asm[128 * 64];
  __shared__ __align__(16) unsigned short Bsm[128 * 64];

  f32x4 acc[4][4];
#pragma unroll
  for (int i = 0; i < 4; ++i)
#pragma unroll
    for (int j = 0; j < 4; ++j) acc[i][j] = (f32x4){0.f, 0.f, 0.f, 0.f};

  const int r_row = tid >> 3;                              // 0..31
  const int dst_k = (tid & 7) * 8;                         // LDS slot (linear)
  const int src_k = ((tid & 7) ^ ((tid >> 3) & 7)) * 8;    // swizzled global chunk
  const int fm = lane & 15;
  const int fq = lane >> 4;                                // quad 0..3

  for (int k0 = 0; k0 < K; k0 += 64) {
#pragma unroll
    for (int i = 0; i < 4; ++i) {
      const int row = i * 32 + r_row;
      gld_lds16(A + (long)(bm + row) * lda + (k0 + src_k), Asm + row * 64 + dst_k);
      gld_lds16(B + (long)(bn + row) * ldb + (k0 + src_k), Bsm + row * 64 + dst_k);
    }
    __syncthreads();
#pragma unroll
    for (int kk = 0; kk < 2; ++kk) {
      bf16x8 af[4], bfr[4];
#pragma unroll
      for (int i = 0; i < 4; ++i) {
        const int pa = ((kk * 4 + fq) ^ (fm & 7)) * 8;
        af[i]  = *(const bf16x8*)(Asm + (wm + i * 16 + fm) * 64 + pa);
        bfr[i] = *(const bf16x8*)(Bsm + (wn + i * 16 + fm) * 64 + pa);
      }
#pragma unroll
      for (int i = 0; i < 4; ++i)
#pragma unroll
        for (int j = 0; j < 4; ++j)
          acc[i][j] = __builtin_amdgcn_mfma_f32_16x16x32_bf16(af[i], bfr[j], acc[i][j], 0, 0, 0);
    }
    __syncthreads();
  }

  const long cb = (long)blockIdx.z * sC;
#pragma unroll
  for (int i = 0; i < 4; ++i) {
#pragma unroll
    for (int j = 0; j < 4; ++j) {
      const int col = bn + wn + j * 16 + fm;       // C/D: col = lane&15
      const float bv = bias ? bias[col] : 0.f;
#pragma unroll
      for (int r = 0; r < 4; ++r) {
        const int row = bm + wm + i * 16 + fq * 4 + r;  // row = quad*4 + reg
        float v = acc[i][j][r] + bv;
        if (RELU) v = fmaxf(v, 0.f);
        if (OUT_BF16)
          ((unsigned short*)Cv)[cb + (long)row * ldc + col] = f2bf(v);
        else
          ((float*)Cv)[cb + (long)row * ldc + col] = v;
      }
    }
  }
}

// ------------- balanced attn GEMM: O = P * Vt^T, dual row-tile -------------
// Block y computes tiles bm_hi=(15-y)*128 (K=2048-128y) and bm_lo=y*128
// (K=128y+128) in ONE K-sweep; total 34 K-iters uniform across all blocks
// (fixes the 10%-occupancy drain of the single-tile K-clamped version).
// V-tile staged once, shared by both accumulators.
__global__ __launch_bounds__(256, 1) void k_attn_pv(
    const unsigned short* __restrict__ P, const unsigned short* __restrict__ Vt,
    unsigned short* __restrict__ O) {
  const int y = blockIdx.y;                 // 0..7
  const int bn = blockIdx.x * 128;          // D col tile
  const int bm_hi = (15 - y) * 128;
  const int bm_lo = y * 128;
  const int Khi = bm_hi + 128;
  const int Klo = bm_lo + 128;
  P  += (long)blockIdx.z * kS * kS;
  Vt += (long)blockIdx.z * kD * kS;
  O  += (long)blockIdx.z * kS * kD;

  const int tid = threadIdx.x;
  const int lane = tid & 63;
  const int wm = ((tid >> 6) >> 1) * 64;
  const int wn = ((tid >> 6) & 1) * 64;

  __shared__ __align__(16) unsigned short Ah[128 * 64];
  __shared__ __align__(16) unsigned short Al[128 * 64];
  __shared__ __align__(16) unsigned short Bs[128 * 64];

  f32x4 ah[4][4], al[4][4];
#pragma unroll
  for (int i = 0; i < 4; ++i)
#pragma unroll
    for (int j = 0; j < 4; ++j) {
      ah[i][j] = (f32x4){0.f, 0.f, 0.f, 0.f};
      al[i][j] = (f32x4){0.f, 0.f, 0.f, 0.f};
    }

  const int r_row = tid >> 3;
  const int dst_k = (tid & 7) * 8;
  const int src_k = ((tid & 7) ^ ((tid >> 3) & 7)) * 8;
  const int fm = lane & 15;
  const int fq = lane >> 4;

  for (int k0 = 0; k0 < Khi; k0 += 64) {
    const bool lo = (k0 < Klo);
#pragma unroll
    for (int i = 0; i < 4; ++i) {
      const int row = i * 32 + r_row;
      gld_lds16(Vt + (long)(bn + row) * kS + (k0 + src_k), Bs + row * 64 + dst_k);
      gld_lds16(P + (long)(bm_hi + row) * kS + (k0 + src_k), Ah + row * 64 + dst_k);
      if (lo)
        gld_lds16(P + (long)(bm_lo + row) * kS + (k0 + src_k), Al + row * 64 + dst_k);
    }
    __syncthreads();
#pragma unroll
    for (int kk = 0; kk < 2; ++kk) {
      bf16x8 afh[4], bfr[4];
#pragma unroll
      for (int i = 0; i < 4; ++i) {
        const int pa = ((kk * 4 + fq) ^ (fm & 7)) * 8;
        afh[i] = *(const bf16x8*)(Ah + (wm + i * 16 + fm) * 64 + pa);
        bfr[i] = *(const bf16x8*)(Bs + (wn + i * 16 + fm) * 64 + pa);
      }
#pragma unroll
      for (int i = 0; i < 4; ++i)
#pragma unroll
        for (int j = 0; j < 4; ++j)
          ah[i][j] = __builtin_amdgcn_mfma_f32_16x16x32_bf16(afh[i], bfr[j], ah[i][j], 0, 0, 0);
      if (lo) {
        bf16x8 afl[4];
#pragma unroll
        for (int i = 0; i < 4; ++i) {
          const int pa = ((kk * 4 + fq) ^ (fm & 7)) * 8;
          afl[i] = *(const bf16x8*)(Al + (wm + i * 16 + fm) * 64 + pa);
        }
#pragma unroll
        for (int i = 0; i < 4; ++i)
#pragma unroll
          for (int j = 0; j < 4; ++j)
            al[i][j] = __builtin_amdgcn_mfma_f32_16x16x32_bf16(afl[i], bfr[j], al[i][j], 0, 0, 0);
      }
    }
    __syncthreads();
  }

#pragma unroll
  for (int i = 0; i < 4; ++i) {
#pragma unroll
    for (int j = 0; j < 4; ++j) {
      const int col = bn + wn + j * 16 + fm;
#pragma unroll
      for (int r = 0; r < 4; ++r) {
        const int rr = wm + i * 16 + fq * 4 + r;
        O[(long)(bm_hi + rr) * kD + col] = f2bf(ah[i][j][r]);
        O[(long)(bm_lo + rr) * kD + col] = f2bf(al[i][j][r]);
      }
    }
  }
}

// ---------------- wave reductions ----------------
DI float wsum(float v) {
  v += __shfl_xor(v, 32, 64);
  v += __shfl_xor(v, 16, 64);
  v += __shfl_xor(v, 8, 64);
  v += __shfl_xor(v, 4, 64);
  v += __shfl_xor(v, 2, 64);
  v += __shfl_xor(v, 1, 64);
  return v;
}
DI float wmax(float v) {
  v = fmaxf(v, __shfl_xor(v, 32, 64));
  v = fmaxf(v, __shfl_xor(v, 16, 64));
  v = fmaxf(v, __shfl_xor(v, 8, 64));
  v = fmaxf(v, __shfl_xor(v, 4, 64));
  v = fmaxf(v, __shfl_xor(v, 2, 64));
  v = fmaxf(v, __shfl_xor(v, 1, 64));
  return v;
}

// ---------------- causal softmax: scores bf16 -> P bf16 ----------------
__global__ __launch_bounds__(256) void k_softmax_causal(
    const unsigned short* __restrict__ S, unsigned short* __restrict__ P) {
  const int row = blockIdx.x;           // 0..8191 flat (b*2048+q)
  const int q = row & (kS - 1);
  const int lim = (q & ~127) + 128;     // attn GEMM reads only k < lim
  const unsigned short* Srow = S + (long)row * kS;
  unsigned short* Prow = P + (long)row * kS;
  const int tid = threadIdx.x;
  __shared__ float red[4];

  float v[8];
  float mx = -INFINITY;
#pragma unroll
  for (int i = 0; i < 8; ++i) {
    const int k = tid + i * 256;
    float xv = -INFINITY;
    if (k <= q) xv = bf2f(Srow[k]) * kScale;
    v[i] = xv;
    mx = fmaxf(mx, xv);
  }
  mx = wmax(mx);
  if ((tid & 63) == 0) red[tid >> 6] = mx;
  __syncthreads();
  mx = fmaxf(fmaxf(red[0], red[1]), fmaxf(red[2], red[3]));
  __syncthreads();  // red reused below

  float sum = 0.f;
#pragma unroll
  for (int i = 0; i < 8; ++i) {
    const float e = (v[i] > -INFINITY) ? __expf(v[i] - mx) : 0.f;
    v[i] = e;
    sum += e;
  }
  sum = wsum(sum);
  if ((tid & 63) == 0) red[tid >> 6] = sum;
  __syncthreads();
  sum = red[0] + red[1] + red[2] + red[3];
  const float inv = 1.f / sum;
#pragma unroll
  for (int i = 0; i < 8; ++i) {
    const int k = tid + i * 256;
    if (k < lim) Prow[k] = f2bf(v[i] * inv);
  }
}

// ------- fused residual + layernorm; X fp32 or bf16, out fp32 or bf16 -------
template <int X_BF16, int OUT_FP32>
__global__ __launch_bounds__(256) void k_residual_ln(
    const void* __restrict__ Xv, const unsigned short* __restrict__ Yb,
    const float* __restrict__ gamma, const float* __restrict__ beta,
    float* __restrict__ Out, unsigned short* __restrict__ OutB) {
  const long base = (long)blockIdx.x * kD;
  const int tid = threadIdx.x;
  __shared__ float reds[4], redss[4];
  float v[4];
  float s = 0.f, ss2 = 0.f;
#pragma unroll
  for (int i = 0; i < 4; ++i) {
    const int k = tid + i * 256;
    const float xf = X_BF16 ? bf2f(((const unsigned short*)Xv)[base + k])
                            : ((const float*)Xv)[base + k];
    const float xv = xf + bf2f(Yb[base + k]);
    v[i] = xv;
    s += xv;
    ss2 += xv * xv;
  }
  s = wsum(s);
  ss2 = wsum(ss2);
  if ((tid & 63) == 0) { reds[tid >> 6] = s; redss[tid >> 6] = ss2; }
  __syncthreads();
  s = reds[0] + reds[1] + reds[2] + reds[3];
  ss2 = redss[0] + redss[1] + redss[2] + redss[3];
  const float mu = s * (1.f / kD);
  float var = ss2 * (1.f / kD) - mu * mu;
  var = fmaxf(var, 0.f);
  const float rstd = rsqrtf(var + kEps);
#pragma unroll
  for (int i = 0; i < 4; ++i) {
    const int k = tid + i * 256;
    const float y = (v[i] - mu) * rstd * gamma[k] + beta[k];
    if (OUT_FP32) Out[base + k] = y;
    else          OutB[base + k] = f2bf(y);
  }
}

extern "C" void kernel_launch(void* const* d_in, const int* in_sizes, int n_in,
                              void* d_out, int out_size, void* d_ws, size_t ws_size,
                              hipStream_t stream) {
  (void)in_sizes; (void)n_in; (void)out_size; (void)ws_size;
  const float* x     = (const float*)d_in[0];
  const float* Wq    = (const float*)d_in[1];
  const float* Wk    = (const float*)d_in[2];
  const float* Wv    = (const float*)d_in[3];
  const float* W1    = (const float*)d_in[4];
  const float* b1    = (const float*)d_in[5];
  const float* W2    = (const float*)d_in[6];
  const float* b2    = (const float*)d_in[7];
  const float* gamma = (const float*)d_in[8];
  const float* beta  = (const float*)d_in[9];
  float* out = (float*)d_out;

  char* base = (char*)d_ws;
  size_t off = 0;
  auto alloc = [&](size_t bytes) -> void* {
    void* p = base + off;
    off = (off + bytes + 255) & ~(size_t)255;
    return p;
  };

  unsigned short* xb     = (unsigned short*)alloc((size_t)kM * kD * 2);       // 16 MB
  unsigned short* Wqkb   = (unsigned short*)alloc((size_t)2 * kD * kD * 2);   // 4 MB
  unsigned short* Wvb    = (unsigned short*)alloc((size_t)kD * kD * 2);       // 2 MB
  unsigned short* W1b    = (unsigned short*)alloc((size_t)kD * kD * 2);       // 2 MB
  unsigned short* W2b    = (unsigned short*)alloc((size_t)kD * kD * 2);       // 2 MB
  unsigned short* QKb    = (unsigned short*)alloc((size_t)kM * 2 * kD * 2);   // 32 MB
  unsigned short* Vt     = (unsigned short*)alloc((size_t)kM * kD * 2);       // 16 MB
  unsigned short* Sb     = (unsigned short*)alloc((size_t)kB * kS * kS * 2);  // 32 MB
  unsigned short* Pb     = (unsigned short*)alloc((size_t)kB * kS * kS * 2);  // 32 MB
  unsigned short* attn_b = (unsigned short*)alloc((size_t)kM * kD * 2);       // 16 MB
  unsigned short* ff_b = attn_b;             // attn dead after LN1
  unsigned short* hb   = Sb;                 // scores dead after softmax
  unsigned short* mid  = Pb;                 // P dead after attn GEMM

  dim3 blk(256);

  // fused casts
  {
    const int n4 = (kM * kD + 5 * kD * kD) / 4;
    k_cast_all<<<n4 / 256, blk, 0, stream>>>(x, Wq, Wk, Wv, W1, W2,
                                             xb, Wqkb, Wvb, W1b, W2b);
  }

  // QK projection: [8192x1024] x [2048x1024]^T -> QK [8192x2048]
  k_gemm_nt<1, 0, 0><<<dim3(2 * kD / 128, kM / 128, 1), blk, 0, stream>>>(
      xb, Wqkb, QKb, nullptr, kM, 2 * kD, kD, kD, kD, 2 * kD, 0, 0, 0);

  // Vt[b] = Wv x_b^T : [1024x1024] x [2048x1024]^T -> [1024x2048] per batch
  k_gemm_nt<1, 0, 0><<<dim3(kS / 128, kD / 128, kB), blk, 0, stream>>>(
      Wvb, xb, Vt, nullptr, kD, kS, kD, kD, kD, kS,
      0, (long)kS * kD, (long)kD * kS);

  // scores = Q K^T (bf16 out), lower-triangle compact grid
  k_gemm_nt<1, 0, 1><<<dim3(136, 1, kB), blk, 0, stream>>>(
      QKb, QKb + kD, Sb, nullptr, kS, kS, kD, 2 * kD, 2 * kD, kS,
      (long)kS * 2 * kD, (long)kS * 2 * kD, (long)kS * kS);

  // causal softmax -> P bf16 (writes only k < diagonal tile edge)
  k_softmax_causal<<<kM, blk, 0, stream>>>(Sb, Pb);

  // attn = P Vt^T, balanced dual-tile blocks (uniform 34 K-iters each)
  k_attn_pv<<<dim3(kD / 128, 8, kB), blk, 0, stream>>>(Pb, Vt, attn_b);

  // h = LN(x + attn) -> bf16 only
  k_residual_ln<0, 0><<<kM, blk, 0, stream>>>(x, attn_b, gamma, beta,
                                              nullptr, hb);

  // FFN
  k_gemm_nt<1, 1, 0><<<dim3(kD / 128, kM / 128, 1), blk, 0, stream>>>(
      hb, W1b, mid, b1, kM, kD, kD, kD, kD, kD, 0, 0, 0);
  k_gemm_nt<1, 0, 0><<<dim3(kD / 128, kM / 128, 1), blk, 0, stream>>>(
      mid, W2b, ff_b, b2, kM, kD, kD, kD, kD, kD, 0, 0, 0);

  // out = LN(h + ff), h read as bf16
  k_residual_ln<1, 1><<<kM, blk, 0, stream>>>(hb, ff_b, gamma, beta,
                                              out, nullptr);
}

// Round 8
// 329.979 us; speedup vs baseline: 1.1172x; 1.0369x over previous
//
#include <hip/hip_runtime.h>
#include <math.h>
#include <cstdint>
#include <cstddef>

#define DI __device__ __forceinline__

typedef __bf16 bf16x8 __attribute__((ext_vector_type(8)));
typedef float f32x4 __attribute__((ext_vector_type(4)));

static constexpr int kB = 4, kS = 2048, kD = 1024;
static constexpr int kM = kB * kS;            // 8192 tokens
static constexpr float kScale = 0.03125f;     // 1/sqrt(1024)
static constexpr float kEps = 1e-5f;

DI unsigned short f2bf(float f) {
  unsigned u = __float_as_uint(f);
  u += 0x7FFFu + ((u >> 16) & 1u);   // round-to-nearest-even
  return (unsigned short)(u >> 16);
}
DI float bf2f(unsigned short h) {
  return __uint_as_float(((unsigned)h) << 16);
}

DI void gld_lds16(const void* g, void* l) {
  __builtin_amdgcn_global_load_lds(
      (__attribute__((address_space(1))) void*)(void*)g,
      (__attribute__((address_space(3))) void*)l, 16, 0, 0);
}

// ------- fused cast fp32 -> bf16 (x, Wq|Wk concat, Wv, W1, W2) -------
__global__ __launch_bounds__(256) void k_cast_all(
    const float* __restrict__ x, const float* __restrict__ Wq,
    const float* __restrict__ Wk, const float* __restrict__ Wv,
    const float* __restrict__ W1, const float* __restrict__ W2,
    unsigned short* __restrict__ xb, unsigned short* __restrict__ Wqkb,
    unsigned short* __restrict__ Wvb, unsigned short* __restrict__ W1b,
    unsigned short* __restrict__ W2b) {
  const int i = blockIdx.x * 256 + threadIdx.x;     // float4 index
  const int X4 = kM * kD / 4;                       // 2,097,152
  const int W4 = kD * kD / 4;                       // 262,144
  const float* src;
  unsigned short* dst;
  int j;
  if (i < X4) { src = x; dst = xb; j = i; }
  else if (i < X4 + W4)     { src = Wq; dst = Wqkb;          j = i - X4; }
  else if (i < X4 + 2 * W4) { src = Wk; dst = Wqkb + 4 * W4; j = i - X4 - W4; }
  else if (i < X4 + 3 * W4) { src = Wv; dst = Wvb;           j = i - X4 - 2 * W4; }
  else if (i < X4 + 4 * W4) { src = W1; dst = W1b;           j = i - X4 - 3 * W4; }
  else                      { src = W2; dst = W2b;           j = i - X4 - 4 * W4; }
  float4 v = ((const float4*)src)[j];
  ushort4 o;
  o.x = f2bf(v.x); o.y = f2bf(v.y); o.z = f2bf(v.z); o.w = f2bf(v.w);
  ((ushort4*)dst)[j] = o;
}

// ---------------- bf16 NT GEMM, 16x16x32 MFMA, XOR-swizzled LDS -------------
// C[M,N] = A[M,K] * B[N,K]^T (+bias, optional relu), batched via blockIdx.z.
// CAUSAL: 0 none; 1 lower-triangle compact grid (blockIdx.x = tri index).
// XCD remap: lin=(lin&7)*(nblk/8)+(lin>>3) gives each XCD a contiguous span.
// LDS tile [row][kchunk]: chunk kc of row r stored at slot kc ^ (r&7);
// fragment ds_read_b128 spreads 8 accesses/bank (0 conflicts measured).
template <int OUT_BF16, int RELU, int CAUSAL>
__global__ __launch_bounds__(256, 2) void k_gemm_nt(
    const unsigned short* __restrict__ A, const unsigned short* __restrict__ B,
    void* __restrict__ Cv, const float* __restrict__ bias,
    int M, int N, int K, int lda, int ldb, int ldc,
    long sA, long sB, long sC) {
  int bm, bn;
  {
    int lin = blockIdx.x + gridDim.x * blockIdx.y;
    const int nblk = gridDim.x * gridDim.y;
    if ((nblk & 7) == 0)
      lin = (lin & 7) * (nblk >> 3) + (lin >> 3);
    if (CAUSAL == 1) {
      const int t = lin;
      int r = (int)floorf((sqrtf(8.f * (float)t + 1.f) - 1.f) * 0.5f);
      while ((r + 1) * (r + 2) / 2 <= t) ++r;
      while (r * (r + 1) / 2 > t) --r;
      bm = r * 128;
      bn = (t - r * (r + 1) / 2) * 128;
    } else {
      bm = (lin / gridDim.x) * 128;
      bn = (lin % gridDim.x) * 128;
    }
  }
  A += (long)blockIdx.z * sA;
  B += (long)blockIdx.z * sB;

  const int tid = threadIdx.x;
  const int lane = tid & 63;
  const int wm = ((tid >> 6) >> 1) * 64;   // wave row offset in tile
  const int wn = ((tid >> 6) & 1) * 64;    // wave col offset in tile

  __shared__ __align__(16) unsigned short Asm[128 * 64];
  __shared__ __align__(16) unsigned short Bsm[128 * 64];

  f32x4 acc[4][4];
#pragma unroll
  for (int i = 0; i < 4; ++i)
#pragma unroll
    for (int j = 0; j < 4; ++j) acc[i][j] = (f32x4){0.f, 0.f, 0.f, 0.f};

  const int r_row = tid >> 3;                              // 0..31
  const int dst_k = (tid & 7) * 8;                         // LDS slot (linear)
  const int src_k = ((tid & 7) ^ ((tid >> 3) & 7)) * 8;    // swizzled global chunk
  const int fm = lane & 15;
  const int fq = lane >> 4;                                // quad 0..3

  for (int k0 = 0; k0 < K; k0 += 64) {
#pragma unroll
    for (int i = 0; i < 4; ++i) {
      const int row = i * 32 + r_row;
      gld_lds16(A + (long)(bm + row) * lda + (k0 + src_k), Asm + row * 64 + dst_k);
      gld_lds16(B + (long)(bn + row) * ldb + (k0 + src_k), Bsm + row * 64 + dst_k);
    }
    __syncthreads();
#pragma unroll
    for (int kk = 0; kk < 2; ++kk) {
      bf16x8 af[4], bfr[4];
#pragma unroll
      for (int i = 0; i < 4; ++i) {
        const int pa = ((kk * 4 + fq) ^ (fm & 7)) * 8;
        af[i]  = *(const bf16x8*)(Asm + (wm + i * 16 + fm) * 64 + pa);
        bfr[i] = *(const bf16x8*)(Bsm + (wn + i * 16 + fm) * 64 + pa);
      }
#pragma unroll
      for (int i = 0; i < 4; ++i)
#pragma unroll
        for (int j = 0; j < 4; ++j)
          acc[i][j] = __builtin_amdgcn_mfma_f32_16x16x32_bf16(af[i], bfr[j], acc[i][j], 0, 0, 0);
    }
    __syncthreads();
  }

  const long cb = (long)blockIdx.z * sC;
#pragma unroll
  for (int i = 0; i < 4; ++i) {
#pragma unroll
    for (int j = 0; j < 4; ++j) {
      const int col = bn + wn + j * 16 + fm;       // C/D: col = lane&15
      const float bv = bias ? bias[col] : 0.f;
#pragma unroll
      for (int r = 0; r < 4; ++r) {
        const int row = bm + wm + i * 16 + fq * 4 + r;  // row = quad*4 + reg
        float v = acc[i][j][r] + bv;
        if (RELU) v = fmaxf(v, 0.f);
        if (OUT_BF16)
          ((unsigned short*)Cv)[cb + (long)row * ldc + col] = f2bf(v);
        else
          ((float*)Cv)[cb + (long)row * ldc + col] = v;
      }
    }
  }
}

// ------- balanced attn GEMM v3: O = P * Vt^T, 64-row dual tile -------------
// 512 blocks (2 co-resident/CU), each computes row-tiles m_hi=31-p (K=2048-64p)
// and m_lo=p (K=64p+64): uniform 33 K-iters/block -> balanced AND overlapped
// (one block's global_load_lds phase hides behind the other's MFMA phase).
// XCD grouping: all 8 x-blocks of one (pair,z) group share lin%8 -> same XCD,
// so each P-tile is fetched into exactly one XCD L2 (~270KB/group).
// Wave layout: wave w covers cols w*32..w*32+31 (j=0..1), rows 0..63 (i=0..3).
__global__ __launch_bounds__(256, 2) void k_attn_pv(
    const unsigned short* __restrict__ P, const unsigned short* __restrict__ Vt,
    unsigned short* __restrict__ O) {
  // decode (x, pair, z) so that the 8 x-blocks of a group share lin%8
  const int r = blockIdx.x;                       // 0..7
  const int q = blockIdx.y + 16 * blockIdx.z;     // 0..63
  const int lx = q & 7;                           // logical x (D col tile)
  const int pq = r + 8 * (q >> 3);                // group id 0..63
  const int pair = pq & 15;
  const int zz = pq >> 4;

  const int bn = lx * 128;
  const int bm_hi = (31 - pair) * 64;
  const int bm_lo = pair * 64;
  const int Khi = bm_hi + 64;
  const int Klo = bm_lo + 64;
  P  += (long)zz * kS * kS;
  Vt += (long)zz * kD * kS;
  O  += (long)zz * kS * kD;

  const int tid = threadIdx.x;
  const int lane = tid & 63;
  const int wn = (tid >> 6) * 32;    // wave col offset (0,32,64,96)

  __shared__ __align__(16) unsigned short Ah[64 * 64];
  __shared__ __align__(16) unsigned short Al[64 * 64];
  __shared__ __align__(16) unsigned short Bs[128 * 64];

  f32x4 ah[4][2], al[4][2];
#pragma unroll
  for (int i = 0; i < 4; ++i)
#pragma unroll
    for (int j = 0; j < 2; ++j) {
      ah[i][j] = (f32x4){0.f, 0.f, 0.f, 0.f};
      al[i][j] = (f32x4){0.f, 0.f, 0.f, 0.f};
    }

  const int r_row = tid >> 3;                              // 0..31
  const int dst_k = (tid & 7) * 8;
  const int src_k = ((tid & 7) ^ ((tid >> 3) & 7)) * 8;
  const int fm = lane & 15;
  const int fq = lane >> 4;

  for (int k0 = 0; k0 < Khi; k0 += 64) {
    const bool lo = (k0 < Klo);
#pragma unroll
    for (int i = 0; i < 2; ++i) {
      const int row = i * 32 + r_row;
      gld_lds16(P + (long)(bm_hi + row) * kS + (k0 + src_k), Ah + row * 64 + dst_k);
      if (lo)
        gld_lds16(P + (long)(bm_lo + row) * kS + (k0 + src_k), Al + row * 64 + dst_k);
    }
#pragma unroll
    for (int i = 0; i < 4; ++i) {
      const int row = i * 32 + r_row;
      gld_lds16(Vt + (long)(bn + row) * kS + (k0 + src_k), Bs + row * 64 + dst_k);
    }
    __syncthreads();
#pragma unroll
    for (int kk = 0; kk < 2; ++kk) {
      bf16x8 afh[4], afl[4], bfr[2];
#pragma unroll
      for (int i = 0; i < 4; ++i) {
        const int ra = i * 16 + fm;
        const int pa = ((kk * 4 + fq) ^ (ra & 7)) * 8;
        afh[i] = *(const bf16x8*)(Ah + ra * 64 + pa);
        afl[i] = *(const bf16x8*)(Al + ra * 64 + pa);
      }
#pragma unroll
      for (int j = 0; j < 2; ++j) {
        const int rb = wn + j * 16 + fm;
        const int pb = ((kk * 4 + fq) ^ (rb & 7)) * 8;
        bfr[j] = *(const bf16x8*)(Bs + rb * 64 + pb);
      }
#pragma unroll
      for (int i = 0; i < 4; ++i)
#pragma unroll
        for (int j = 0; j < 2; ++j)
          ah[i][j] = __builtin_amdgcn_mfma_f32_16x16x32_bf16(afh[i], bfr[j], ah[i][j], 0, 0, 0);
      if (lo) {
#pragma unroll
        for (int i = 0; i < 4; ++i)
#pragma unroll
          for (int j = 0; j < 2; ++j)
            al[i][j] = __builtin_amdgcn_mfma_f32_16x16x32_bf16(afl[i], bfr[j], al[i][j], 0, 0, 0);
      }
    }
    __syncthreads();
  }

#pragma unroll
  for (int i = 0; i < 4; ++i) {
#pragma unroll
    for (int j = 0; j < 2; ++j) {
      const int col = bn + wn + j * 16 + fm;
#pragma unroll
      for (int r2 = 0; r2 < 4; ++r2) {
        const int rr = i * 16 + fq * 4 + r2;
        O[(long)(bm_hi + rr) * kD + col] = f2bf(ah[i][j][r2]);
        O[(long)(bm_lo + rr) * kD + col] = f2bf(al[i][j][r2]);
      }
    }
  }
}

// ---------------- wave reductions ----------------
DI float wsum(float v) {
  v += __shfl_xor(v, 32, 64);
  v += __shfl_xor(v, 16, 64);
  v += __shfl_xor(v, 8, 64);
  v += __shfl_xor(v, 4, 64);
  v += __shfl_xor(v, 2, 64);
  v += __shfl_xor(v, 1, 64);
  return v;
}
DI float wmax(float v) {
  v = fmaxf(v, __shfl_xor(v, 32, 64));
  v = fmaxf(v, __shfl_xor(v, 16, 64));
  v = fmaxf(v, __shfl_xor(v, 8, 64));
  v = fmaxf(v, __shfl_xor(v, 4, 64));
  v = fmaxf(v, __shfl_xor(v, 2, 64));
  v = fmaxf(v, __shfl_xor(v, 1, 64));
  return v;
}

// ---------------- causal softmax: scores bf16 -> P bf16 ----------------
__global__ __launch_bounds__(256) void k_softmax_causal(
    const unsigned short* __restrict__ S, unsigned short* __restrict__ P) {
  const int row = blockIdx.x;           // 0..8191 flat (b*2048+q)
  const int q = row & (kS - 1);
  const int lim = (q & ~127) + 128;     // attn GEMM reads only k < lim
  const unsigned short* Srow = S + (long)row * kS;
  unsigned short* Prow = P + (long)row * kS;
  const int tid = threadIdx.x;
  __shared__ float red[4];

  float v[8];
  float mx = -INFINITY;
#pragma unroll
  for (int i = 0; i < 8; ++i) {
    const int k = tid + i * 256;
    float xv = -INFINITY;
    if (k <= q) xv = bf2f(Srow[k]) * kScale;
    v[i] = xv;
    mx = fmaxf(mx, xv);
  }
  mx = wmax(mx);
  if ((tid & 63) == 0) red[tid >> 6] = mx;
  __syncthreads();
  mx = fmaxf(fmaxf(red[0], red[1]), fmaxf(red[2], red[3]));
  __syncthreads();  // red reused below

  float sum = 0.f;
#pragma unroll
  for (int i = 0; i < 8; ++i) {
    const float e = (v[i] > -INFINITY) ? __expf(v[i] - mx) : 0.f;
    v[i] = e;
    sum += e;
  }
  sum = wsum(sum);
  if ((tid & 63) == 0) red[tid >> 6] = sum;
  __syncthreads();
  sum = red[0] + red[1] + red[2] + red[3];
  const float inv = 1.f / sum;
#pragma unroll
  for (int i = 0; i < 8; ++i) {
    const int k = tid + i * 256;
    if (k < lim) Prow[k] = f2bf(v[i] * inv);
  }
}

// ------- fused residual + layernorm; X fp32 or bf16, out fp32 or bf16 -------
template <int X_BF16, int OUT_FP32>
__global__ __launch_bounds__(256) void k_residual_ln(
    const void* __restrict__ Xv, const unsigned short* __restrict__ Yb,
    const float* __restrict__ gamma, const float* __restrict__ beta,
    float* __restrict__ Out, unsigned short* __restrict__ OutB) {
  const long base = (long)blockIdx.x * kD;
  const int tid = threadIdx.x;
  __shared__ float reds[4], redss[4];
  float v[4];
  float s = 0.f, ss2 = 0.f;
#pragma unroll
  for (int i = 0; i < 4; ++i) {
    const int k = tid + i * 256;
    const float xf = X_BF16 ? bf2f(((const unsigned short*)Xv)[base + k])
                            : ((const float*)Xv)[base + k];
    const float xv = xf + bf2f(Yb[base + k]);
    v[i] = xv;
    s += xv;
    ss2 += xv * xv;
  }
  s = wsum(s);
  ss2 = wsum(ss2);
  if ((tid & 63) == 0) { reds[tid >> 6] = s; redss[tid >> 6] = ss2; }
  __syncthreads();
  s = reds[0] + reds[1] + reds[2] + reds[3];
  ss2 = redss[0] + redss[1] + redss[2] + redss[3];
  const float mu = s * (1.f / kD);
  float var = ss2 * (1.f / kD) - mu * mu;
  var = fmaxf(var, 0.f);
  const float rstd = rsqrtf(var + kEps);
#pragma unroll
  for (int i = 0; i < 4; ++i) {
    const int k = tid + i * 256;
    const float y = (v[i] - mu) * rstd * gamma[k] + beta[k];
    if (OUT_FP32) Out[base + k] = y;
    else          OutB[base + k] = f2bf(y);
  }
}

extern "C" void kernel_launch(void* const* d_in, const int* in_sizes, int n_in,
                              void* d_out, int out_size, void* d_ws, size_t ws_size,
                              hipStream_t stream) {
  (void)in_sizes; (void)n_in; (void)out_size; (void)ws_size;
  const float* x     = (const float*)d_in[0];
  const float* Wq    = (const float*)d_in[1];
  const float* Wk    = (const float*)d_in[2];
  const float* Wv    = (const float*)d_in[3];
  const float* W1    = (const float*)d_in[4];
  const float* b1    = (const float*)d_in[5];
  const float* W2    = (const float*)d_in[6];
  const float* b2    = (const float*)d_in[7];
  const float* gamma = (const float*)d_in[8];
  const float* beta  = (const float*)d_in[9];
  float* out = (float*)d_out;

  char* base = (char*)d_ws;
  size_t off = 0;
  auto alloc = [&](size_t bytes) -> void* {
    void* p = base + off;
    off = (off + bytes + 255) & ~(size_t)255;
    return p;
  };

  unsigned short* xb     = (unsigned short*)alloc((size_t)kM * kD * 2);       // 16 MB
  unsigned short* Wqkb   = (unsigned short*)alloc((size_t)2 * kD * kD * 2);   // 4 MB
  unsigned short* Wvb    = (unsigned short*)alloc((size_t)kD * kD * 2);       // 2 MB
  unsigned short* W1b    = (unsigned short*)alloc((size_t)kD * kD * 2);       // 2 MB
  unsigned short* W2b    = (unsigned short*)alloc((size_t)kD * kD * 2);       // 2 MB
  unsigned short* QKb    = (unsigned short*)alloc((size_t)kM * 2 * kD * 2);   // 32 MB
  unsigned short* Vt     = (unsigned short*)alloc((size_t)kM * kD * 2);       // 16 MB
  unsigned short* Sb     = (unsigned short*)alloc((size_t)kB * kS * kS * 2);  // 32 MB
  unsigned short* Pb     = (unsigned short*)alloc((size_t)kB * kS * kS * 2);  // 32 MB
  unsigned short* attn_b = (unsigned short*)alloc((size_t)kM * kD * 2);       // 16 MB
  unsigned short* ff_b = attn_b;             // attn dead after LN1
  unsigned short* hb   = Sb;                 // scores dead after softmax
  unsigned short* mid  = Pb;                 // P dead after attn GEMM

  dim3 blk(256);

  // fused casts
  {
    const int n4 = (kM * kD + 5 * kD * kD) / 4;
    k_cast_all<<<n4 / 256, blk, 0, stream>>>(x, Wq, Wk, Wv, W1, W2,
                                             xb, Wqkb, Wvb, W1b, W2b);
  }

  // QK projection: [8192x1024] x [2048x1024]^T -> QK [8192x2048]
  k_gemm_nt<1, 0, 0><<<dim3(2 * kD / 128, kM / 128, 1), blk, 0, stream>>>(
      xb, Wqkb, QKb, nullptr, kM, 2 * kD, kD, kD, kD, 2 * kD, 0, 0, 0);

  // Vt[b] = Wv x_b^T : [1024x1024] x [2048x1024]^T -> [1024x2048] per batch
  k_gemm_nt<1, 0, 0><<<dim3(kS / 128, kD / 128, kB), blk, 0, stream>>>(
      Wvb, xb, Vt, nullptr, kD, kS, kD, kD, kD, kS,
      0, (long)kS * kD, (long)kD * kS);

  // scores = Q K^T (bf16 out), lower-triangle compact grid
  k_gemm_nt<1, 0, 1><<<dim3(136, 1, kB), blk, 0, stream>>>(
      QKb, QKb + kD, Sb, nullptr, kS, kS, kD, 2 * kD, 2 * kD, kS,
      (long)kS * 2 * kD, (long)kS * 2 * kD, (long)kS * kS);

  // causal softmax -> P bf16 (writes only k < diagonal tile edge)
  k_softmax_causal<<<kM, blk, 0, stream>>>(Sb, Pb);

  // attn = P Vt^T, balanced 64-row dual-tile (uniform 33 K-iters, 512 blocks)
  k_attn_pv<<<dim3(8, 16, kB), blk, 0, stream>>>(Pb, Vt, attn_b);

  // h = LN(x + attn) -> bf16 only
  k_residual_ln<0, 0><<<kM, blk, 0, stream>>>(x, attn_b, gamma, beta,
                                              nullptr, hb);

  // FFN
  k_gemm_nt<1, 1, 0><<<dim3(kD / 128, kM / 128, 1), blk, 0, stream>>>(
      hb, W1b, mid, b1, kM, kD, kD, kD, kD, kD, 0, 0, 0);
  k_gemm_nt<1, 0, 0><<<dim3(kD / 128, kM / 128, 1), blk, 0, stream>>>(
      mid, W2b, ff_b, b2, kM, kD, kD, kD, kD, kD, 0, 0, 0);

  // out = LN(h + ff), h read as bf16
  k_residual_ln<1, 1><<<kM, blk, 0, stream>>>(hb, ff_b, gamma, beta,
                                              out, nullptr);
}